// Round 2
// baseline (2039.509 us; speedup 1.0000x reference)
//
#include <hip/hip_runtime.h>
#include <hip/hip_bf16.h>
#include <stdint.h>

#define N_NODES_C 262144
#define N_EDGES_C 2097152
#define NB_C      8192      // graphs
#define NEG_SLOPE_C 0.2f

typedef __attribute__((ext_vector_type(4))) float f32x4;

// monotonic float<->uint mapping for atomicMax on floats
static __device__ __forceinline__ unsigned int fmap(float f) {
    unsigned int b = __builtin_bit_cast(unsigned int, f);
    return (b & 0x80000000u) ? ~b : (b | 0x80000000u);
}
static __device__ __forceinline__ float funmap(unsigned int u) {
    unsigned int b = (u & 0x80000000u) ? (u & 0x7fffffffu) : ~u;
    return __builtin_bit_cast(float, b);
}

// ---------------- utility ----------------
__global__ void zero_f32(float* __restrict__ p, int n4) {
    int i = blockIdx.x * blockDim.x + threadIdx.x;
    int stride = gridDim.x * blockDim.x;
    f32x4 z = {0.f, 0.f, 0.f, 0.f};
    for (int k = i; k < n4; k += stride) ((f32x4*)p)[k] = z;
}

// ---------------- node transform: h = X @ W, a_s = h.att_s, a_d = h.att_d ----
// LAYER 1: xin = x (f32). LAYER 2: xin = agg (f32), add previous layer's bias
// (b1) per input channel on read.
template <int LAYER>
__global__ __launch_bounds__(256) void transform_f32(
    const float* __restrict__ xin,
    const float* __restrict__ W,       // [64][64] f32: W[k][o]
    const float* __restrict__ att_s,   // [64]
    const float* __restrict__ att_d,   // [64]
    const float* __restrict__ bias_in, // [64] (layer2 only: b1)
    float* __restrict__ h, float* __restrict__ a_s, float* __restrict__ a_d)
{
    __shared__ float Ws[64 * 64];
    for (int i = threadIdx.x; i < 64 * 64; i += 256) Ws[i] = W[i];
    __syncthreads();

    const int lane = threadIdx.x & 63;
    const int wid  = threadIdx.x >> 6;
    const float atS = att_s[lane];
    const float atD = att_d[lane];
    float bin = 0.f;
    if constexpr (LAYER == 2) bin = bias_in[lane];

    int node = blockIdx.x * 4 + wid;
    const int stride = gridDim.x * 4;
    for (; node < N_NODES_C; node += stride) {
        float xr = xin[node * 64 + lane];
        if constexpr (LAYER == 2) xr += bin;
        float acc = 0.f;
        #pragma unroll
        for (int k = 0; k < 64; ++k) {
            float xk = __shfl(xr, k, 64);
            acc += xk * Ws[k * 64 + lane];
        }
        h[node * 64 + lane] = acc;
        float ps = acc * atS, pd = acc * atD;
        #pragma unroll
        for (int m = 1; m < 64; m <<= 1) {
            ps += __shfl_xor(ps, m, 64);
            pd += __shfl_xor(pd, m, 64);
        }
        if (lane == 0) { a_s[node] = ps; a_d[node] = pd; }
    }
}

// ---------------- edge passes ----------------
__global__ void edge_pass1(const int* __restrict__ src, const int* __restrict__ dst,
                           const float* __restrict__ a_s, const float* __restrict__ a_d,
                           float* __restrict__ ebuf, unsigned int* __restrict__ m)
{
    int i = blockIdx.x * blockDim.x + threadIdx.x;
    int stride = gridDim.x * blockDim.x;
    for (int e = i; e < N_EDGES_C; e += stride) {
        int s = src[e], d = dst[e];
        float v = a_s[s] + a_d[d];
        v = v > 0.f ? v : NEG_SLOPE_C * v;
        ebuf[e] = v;
        atomicMax(&m[d], fmap(v));
    }
}

__global__ void edge_pass2(const int* __restrict__ dst,
                           const unsigned int* __restrict__ m,
                           float* __restrict__ ebuf, float* __restrict__ ssum)
{
    int i = blockIdx.x * blockDim.x + threadIdx.x;
    int stride = gridDim.x * blockDim.x;
    for (int e = i; e < N_EDGES_C; e += stride) {
        int d = dst[e];
        float p = __expf(ebuf[e] - funmap(m[d]));
        ebuf[e] = p;
        atomicAdd(&ssum[d], p);
    }
}

__global__ void edge_pass3(const int* __restrict__ src, const int* __restrict__ dst,
                           const float* __restrict__ ebuf, const float* __restrict__ ssum,
                           const float* __restrict__ h, float* __restrict__ agg)
{
    int lane = threadIdx.x & 63;
    int wid = (blockIdx.x * blockDim.x + threadIdx.x) >> 6;
    int nw  = (gridDim.x * blockDim.x) >> 6;
    for (int e = wid; e < N_EDGES_C; e += nw) {
        int s = src[e], d = dst[e];
        float alpha = ebuf[e] / ssum[d];
        float v = alpha * h[s * 64 + lane];
        atomicAdd(&agg[d * 64 + lane], v);
    }
}

// ---------------- FC head ----------------
// g[b][k] = agg[b*2048+k] + b2[k&63];  f = relu(g @ Wf1 + bf1)
__global__ __launch_bounds__(256) void fc1_f32(
    const float* __restrict__ agg, const float* __restrict__ b2,
    const float* __restrict__ Wf1,   // [2048][256] f32
    const float* __restrict__ bf1,   // [256]
    float* __restrict__ fbuf)        // [8192][256]
{
    __shared__ float gs[8][2048];
    const int bb = blockIdx.x * 8;   // 1024 blocks
    #pragma unroll
    for (int r = 0; r < 8; ++r)
        for (int k = threadIdx.x; k < 2048; k += 256)
            gs[r][k] = agg[(size_t)(bb + r) * 2048 + k] + b2[k & 63];
    __syncthreads();

    const int o = threadIdx.x;
    float acc[8];
    const float bias = bf1[o];
    #pragma unroll
    for (int r = 0; r < 8; ++r) acc[r] = bias;
    for (int k = 0; k < 2048; ++k) {
        float w = Wf1[k * 256 + o];
        #pragma unroll
        for (int r = 0; r < 8; ++r) acc[r] += gs[r][k] * w;
    }
    #pragma unroll
    for (int r = 0; r < 8; ++r) {
        float v = acc[r];
        fbuf[(size_t)(bb + r) * 256 + o] = v > 0.f ? v : 0.f;
    }
}

__global__ __launch_bounds__(256) void fc2_f32(
    const float* __restrict__ fbuf, const float* __restrict__ Wf2, // [256][32]
    const float* __restrict__ bf2v, float* __restrict__ out)       // [8192][32]
{
    __shared__ float w[256 * 32];
    for (int i = threadIdx.x; i < 256 * 32; i += 256) w[i] = Wf2[i];
    __syncthreads();
    int tid = blockIdx.x * 256 + threadIdx.x;
    int b = tid >> 5, o = tid & 31;
    float acc = bf2v[o];
    const float* fp = fbuf + (size_t)b * 256;
    for (int j = 0; j < 256; j += 4) {
        f32x4 f4 = *(const f32x4*)(fp + j);
        acc += f4[0] * w[(j + 0) * 32 + o];
        acc += f4[1] * w[(j + 1) * 32 + o];
        acc += f4[2] * w[(j + 2) * 32 + o];
        acc += f4[3] * w[(j + 3) * 32 + o];
    }
    out[(size_t)b * 32 + o] = acc;
}

// ---------------- launch ----------------
extern "C" void kernel_launch(void* const* d_in, const int* in_sizes, int n_in,
                              void* d_out, int out_size, void* d_ws, size_t ws_size,
                              hipStream_t stream)
{
    const float* x    = (const float*)d_in[0];
    const int*   ei   = (const int*)d_in[1];
    const float* W1   = (const float*)d_in[2];
    const float* as1  = (const float*)d_in[3];
    const float* ad1  = (const float*)d_in[4];
    const float* b1   = (const float*)d_in[5];
    const float* W2   = (const float*)d_in[6];
    const float* as2  = (const float*)d_in[7];
    const float* ad2  = (const float*)d_in[8];
    const float* b2   = (const float*)d_in[9];
    const float* Wf1  = (const float*)d_in[10];
    const float* bf1  = (const float*)d_in[11];
    const float* Wf2  = (const float*)d_in[12];
    const float* bf2v = (const float*)d_in[13];

    const int* src = ei;
    const int* dst = ei + N_EDGES_C;

    char* ws = (char*)d_ws;
    float* h            = (float*)ws;         ws += (size_t)N_NODES_C * 64 * 4;
    float* agg          = (float*)ws;         ws += (size_t)N_NODES_C * 64 * 4;
    unsigned int* m     = (unsigned int*)ws;  ws += (size_t)N_NODES_C * 4;
    float* ssum         = (float*)ws;         ws += (size_t)N_NODES_C * 4;
    float* a_s          = (float*)ws;         ws += (size_t)N_NODES_C * 4;
    float* a_d          = (float*)ws;         ws += (size_t)N_NODES_C * 4;
    float* ebuf         = (float*)ws;         ws += (size_t)N_EDGES_C * 4;
    float* fbuf         = (float*)ws;         ws += (size_t)NB_C * 256 * 4;

    // agg, m, ssum are contiguous -> one zeroing pass covers all three
    const int zeroN4 = (N_NODES_C * 64 + 2 * N_NODES_C) / 4;

    // ---- layer 1 ----
    zero_f32<<<2048, 256, 0, stream>>>(agg, zeroN4);
    transform_f32<1><<<2048, 256, 0, stream>>>(x, W1, as1, ad1, nullptr, h, a_s, a_d);
    edge_pass1<<<2048, 256, 0, stream>>>(src, dst, a_s, a_d, ebuf, m);
    edge_pass2<<<2048, 256, 0, stream>>>(dst, m, ebuf, ssum);
    edge_pass3<<<8192, 256, 0, stream>>>(src, dst, ebuf, ssum, h, agg);

    // ---- layer 2 (transform reads agg BEFORE it is re-zeroed) ----
    transform_f32<2><<<2048, 256, 0, stream>>>(agg, W2, as2, ad2, b1, h, a_s, a_d);
    zero_f32<<<2048, 256, 0, stream>>>(agg, zeroN4);
    edge_pass1<<<2048, 256, 0, stream>>>(src, dst, a_s, a_d, ebuf, m);
    edge_pass2<<<2048, 256, 0, stream>>>(dst, m, ebuf, ssum);
    edge_pass3<<<8192, 256, 0, stream>>>(src, dst, ebuf, ssum, h, agg);

    // ---- FC head ----
    fc1_f32<<<1024, 256, 0, stream>>>(agg, b2, Wf1, bf1, fbuf);
    fc2_f32<<<1024, 256, 0, stream>>>(fbuf, Wf2, bf2v, (float*)d_out);
}

// Round 3
// 1348.166 us; speedup vs baseline: 1.5128x; 1.5128x over previous
//
#include <hip/hip_runtime.h>
#include <stdint.h>

#define N_NODES_C 262144
#define N_EDGES_C 2097152
#define NB_C      8192      // graphs
#define NEG_SLOPE_C 0.2f

typedef __attribute__((ext_vector_type(4))) float f32x4;
typedef unsigned int u32;

static __device__ __forceinline__ unsigned short f2bf(float f) {
    unsigned int u = __builtin_bit_cast(unsigned int, f);
    unsigned int r = (u + 0x7FFFu + ((u >> 16) & 1u)) >> 16;
    return (unsigned short)r;
}
static __device__ __forceinline__ float bf2f(unsigned short u) {
    unsigned int x = ((unsigned int)u) << 16;
    return __builtin_bit_cast(float, x);
}

// ---------------- CSR build ----------------
__global__ void zero_u32(u32* __restrict__ p, int n) {
    int i = blockIdx.x * blockDim.x + threadIdx.x;
    int stride = gridDim.x * blockDim.x;
    for (int k = i; k < n; k += stride) p[k] = 0u;
}

__global__ void hist_kernel(const int* __restrict__ dst, u32* __restrict__ counts) {
    int i = blockIdx.x * blockDim.x + threadIdx.x;
    int stride = gridDim.x * blockDim.x;
    for (int e = i; e < N_EDGES_C; e += stride)
        atomicAdd(&counts[dst[e]], 1u);
}

// 262144 counts = 256 blocks x 1024 elems (4/thread)
__global__ __launch_bounds__(256) void scan_a(const u32* __restrict__ counts,
                                              u32* __restrict__ row_start,
                                              u32* __restrict__ partials) {
    __shared__ u32 sd[256];
    const int t = threadIdx.x;
    const int base = blockIdx.x * 1024 + t * 4;
    uint4 c = *(const uint4*)(counts + base);
    u32 s = c.x + c.y + c.z + c.w;
    sd[t] = s;
    __syncthreads();
    for (int off = 1; off < 256; off <<= 1) {
        u32 v = (t >= off) ? sd[t - off] : 0u;
        __syncthreads();
        sd[t] += v;
        __syncthreads();
    }
    u32 excl = sd[t] - s;
    row_start[base + 0] = excl;
    row_start[base + 1] = excl + c.x;
    row_start[base + 2] = excl + c.x + c.y;
    row_start[base + 3] = excl + c.x + c.y + c.z;
    if (t == 255) partials[blockIdx.x] = sd[255];
}

__global__ __launch_bounds__(256) void scan_b(u32* __restrict__ partials) {
    __shared__ u32 sd[256];
    const int t = threadIdx.x;
    u32 s = partials[t];
    sd[t] = s;
    __syncthreads();
    for (int off = 1; off < 256; off <<= 1) {
        u32 v = (t >= off) ? sd[t - off] : 0u;
        __syncthreads();
        sd[t] += v;
        __syncthreads();
    }
    partials[t] = sd[t] - s;   // exclusive block offsets
}

__global__ __launch_bounds__(256) void scan_c(u32* __restrict__ row_start,
                                              u32* __restrict__ cursor,
                                              const u32* __restrict__ partials) {
    int i = blockIdx.x * 256 + threadIdx.x;  // 1024 blocks
    u32 v = row_start[i] + partials[i >> 10];
    row_start[i] = v;
    cursor[i] = v;
    if (i == 0) row_start[N_NODES_C] = N_EDGES_C;
}

__global__ void scatter_kernel(const int* __restrict__ src, const int* __restrict__ dst,
                               u32* __restrict__ cursor, int* __restrict__ sorted_src) {
    int i = blockIdx.x * blockDim.x + threadIdx.x;
    int stride = gridDim.x * blockDim.x;
    for (int e = i; e < N_EDGES_C; e += stride) {
        u32 pos = atomicAdd(&cursor[dst[e]], 1u);
        sorted_src[pos] = src[e];
    }
}

// ---------------- node transform: h = X @ W (bf16 out), a_s, a_d ----------------
template <int LAYER>
__global__ __launch_bounds__(256) void transform_f32(
    const float* __restrict__ xin,
    const float* __restrict__ W,       // [64][64]: W[k][o]
    const float* __restrict__ att_s, const float* __restrict__ att_d,
    const float* __restrict__ bias_in, // layer2 only: b1
    unsigned short* __restrict__ h_bf,
    float* __restrict__ a_s, float* __restrict__ a_d)
{
    __shared__ float Ws[64 * 64];
    for (int i = threadIdx.x; i < 64 * 64; i += 256) Ws[i] = W[i];
    __syncthreads();

    const int lane = threadIdx.x & 63;
    const int wid  = threadIdx.x >> 6;
    const float atS = att_s[lane];
    const float atD = att_d[lane];
    float bin = 0.f;
    if constexpr (LAYER == 2) bin = bias_in[lane];

    int node = blockIdx.x * 4 + wid;
    const int stride = gridDim.x * 4;
    for (; node < N_NODES_C; node += stride) {
        float xr = xin[(size_t)node * 64 + lane];
        if constexpr (LAYER == 2) xr += bin;
        float acc = 0.f;
        #pragma unroll
        for (int k = 0; k < 64; ++k) {
            float xk = __shfl(xr, k, 64);
            acc += xk * Ws[k * 64 + lane];
        }
        h_bf[(size_t)node * 64 + lane] = f2bf(acc);
        float ps = acc * atS, pd = acc * atD;
        #pragma unroll
        for (int m = 1; m < 64; m <<= 1) {
            ps += __shfl_xor(ps, m, 64);
            pd += __shfl_xor(pd, m, 64);
        }
        if (lane == 0) { a_s[node] = ps; a_d[node] = pd; }
    }
}

// ---------------- fused GAT aggregate (per dst node, no atomics) ----------------
__global__ __launch_bounds__(256) void gat_aggregate(
    const u32* __restrict__ row_start, const int* __restrict__ sorted_src,
    const float* __restrict__ a_s, const float* __restrict__ a_d,
    const unsigned short* __restrict__ h_bf, float* __restrict__ agg)
{
    const int lane = threadIdx.x & 63;
    const int wid = (blockIdx.x * blockDim.x + threadIdx.x) >> 6;
    const int nw  = (gridDim.x * blockDim.x) >> 6;
    for (int node = wid; node < N_NODES_C; node += nw) {
        const u32 beg = row_start[node], end = row_start[node + 1];
        float acc = 0.f;
        if (beg < end) {
            const float ad = a_d[node];
            float m = -3.0e38f, l = 0.f;
            for (u32 base = beg; base < end; base += 64) {
                u32 i = base + lane;
                bool valid = i < end;
                int s = valid ? sorted_src[i] : 0;
                float e = valid ? a_s[s] + ad : -3.0e38f;
                e = e > 0.f ? e : NEG_SLOPE_C * e;
                float cm = e;
                #pragma unroll
                for (int off = 32; off; off >>= 1) cm = fmaxf(cm, __shfl_xor(cm, off, 64));
                float mn = fmaxf(m, cm);
                float p = valid ? __expf(e - mn) : 0.f;
                #pragma unroll
                for (int off = 32; off; off >>= 1) p += __shfl_xor(p, off, 64);
                l = l * __expf(m - mn) + p;
                m = mn;
            }
            const float inv = 1.f / l;
            for (u32 base = beg; base < end; base += 64) {
                u32 i = base + lane;
                bool valid = i < end;
                int s = valid ? sorted_src[i] : 0;
                float e = valid ? a_s[s] + ad : 0.f;
                e = e > 0.f ? e : NEG_SLOPE_C * e;
                float alpha = valid ? __expf(e - m) * inv : 0.f;
                int cnt = (int)min(64u, end - base);
                for (int j = 0; j < cnt; ++j) {
                    float al = __shfl(alpha, j, 64);
                    int sj = __shfl(s, j, 64);
                    acc += al * bf2f(h_bf[(size_t)sj * 64 + lane]);
                }
            }
        }
        agg[(size_t)node * 64 + lane] = acc;
    }
}

// ---------------- FC head ----------------
__global__ __launch_bounds__(256) void fc1_f32(
    const float* __restrict__ agg, const float* __restrict__ b2,
    const float* __restrict__ Wf1,   // [2048][256]
    const float* __restrict__ bf1,   // [256]
    float* __restrict__ fbuf)        // [8192][256]
{
    __shared__ float gs[8][2048];
    const int bb = blockIdx.x * 8;   // 1024 blocks
    #pragma unroll
    for (int r = 0; r < 8; ++r)
        for (int k = threadIdx.x; k < 2048; k += 256)
            gs[r][k] = agg[(size_t)(bb + r) * 2048 + k] + b2[k & 63];
    __syncthreads();

    const int o = threadIdx.x;
    float acc[8];
    const float bias = bf1[o];
    #pragma unroll
    for (int r = 0; r < 8; ++r) acc[r] = bias;
    for (int k = 0; k < 2048; ++k) {
        float w = Wf1[k * 256 + o];
        #pragma unroll
        for (int r = 0; r < 8; ++r) acc[r] += gs[r][k] * w;
    }
    #pragma unroll
    for (int r = 0; r < 8; ++r) {
        float v = acc[r];
        fbuf[(size_t)(bb + r) * 256 + o] = v > 0.f ? v : 0.f;
    }
}

__global__ __launch_bounds__(256) void fc2_f32(
    const float* __restrict__ fbuf, const float* __restrict__ Wf2, // [256][32]
    const float* __restrict__ bf2v, float* __restrict__ out)
{
    __shared__ float w[256 * 32];
    for (int i = threadIdx.x; i < 256 * 32; i += 256) w[i] = Wf2[i];
    __syncthreads();
    int tid = blockIdx.x * 256 + threadIdx.x;
    int b = tid >> 5, o = tid & 31;
    float acc = bf2v[o];
    const float* fp = fbuf + (size_t)b * 256;
    for (int j = 0; j < 256; j += 4) {
        f32x4 f4 = *(const f32x4*)(fp + j);
        acc += f4[0] * w[(j + 0) * 32 + o];
        acc += f4[1] * w[(j + 1) * 32 + o];
        acc += f4[2] * w[(j + 2) * 32 + o];
        acc += f4[3] * w[(j + 3) * 32 + o];
    }
    out[(size_t)b * 32 + o] = acc;
}

// ---------------- launch ----------------
extern "C" void kernel_launch(void* const* d_in, const int* in_sizes, int n_in,
                              void* d_out, int out_size, void* d_ws, size_t ws_size,
                              hipStream_t stream)
{
    const float* x    = (const float*)d_in[0];
    const int*   ei   = (const int*)d_in[1];
    const float* W1   = (const float*)d_in[2];
    const float* as1  = (const float*)d_in[3];
    const float* ad1  = (const float*)d_in[4];
    const float* b1   = (const float*)d_in[5];
    const float* W2   = (const float*)d_in[6];
    const float* as2  = (const float*)d_in[7];
    const float* ad2  = (const float*)d_in[8];
    const float* b2   = (const float*)d_in[9];
    const float* Wf1  = (const float*)d_in[10];
    const float* bf1  = (const float*)d_in[11];
    const float* Wf2  = (const float*)d_in[12];
    const float* bf2v = (const float*)d_in[13];

    const int* src = ei;
    const int* dst = ei + N_EDGES_C;

    char* ws = (char*)d_ws;
    unsigned short* h_bf = (unsigned short*)ws; ws += (size_t)N_NODES_C * 64 * 2;
    float* agg          = (float*)ws;          ws += (size_t)N_NODES_C * 64 * 4;
    float* a_s          = (float*)ws;          ws += (size_t)N_NODES_C * 4;
    float* a_d          = (float*)ws;          ws += (size_t)N_NODES_C * 4;
    u32* counts         = (u32*)ws;            ws += (size_t)N_NODES_C * 4;
    u32* row_start      = (u32*)ws;            ws += (size_t)(N_NODES_C + 4) * 4;
    u32* cursor         = (u32*)ws;            ws += (size_t)N_NODES_C * 4;
    int* sorted_src     = (int*)ws;            ws += (size_t)N_EDGES_C * 4;
    u32* partials       = (u32*)ws;            ws += 256 * 4;
    float* fbuf         = (float*)ws;          ws += (size_t)NB_C * 256 * 4;

    // ---- CSR build (edge_index only; shared by both layers) ----
    zero_u32<<<256, 256, 0, stream>>>(counts, N_NODES_C);
    hist_kernel<<<2048, 256, 0, stream>>>(dst, counts);
    scan_a<<<256, 256, 0, stream>>>(counts, row_start, partials);
    scan_b<<<1, 256, 0, stream>>>(partials);
    scan_c<<<1024, 256, 0, stream>>>(row_start, cursor, partials);
    scatter_kernel<<<2048, 256, 0, stream>>>(src, dst, cursor, sorted_src);

    // ---- layer 1 ----
    transform_f32<1><<<2048, 256, 0, stream>>>(x, W1, as1, ad1, nullptr, h_bf, a_s, a_d);
    gat_aggregate<<<16384, 256, 0, stream>>>(row_start, sorted_src, a_s, a_d, h_bf, agg);

    // ---- layer 2 ----
    transform_f32<2><<<2048, 256, 0, stream>>>(agg, W2, as2, ad2, b1, h_bf, a_s, a_d);
    gat_aggregate<<<16384, 256, 0, stream>>>(row_start, sorted_src, a_s, a_d, h_bf, agg);

    // ---- FC head ----
    fc1_f32<<<1024, 256, 0, stream>>>(agg, b2, Wf1, bf1, fbuf);
    fc2_f32<<<1024, 256, 0, stream>>>(fbuf, Wf2, bf2v, (float*)d_out);
}

// Round 4
// 767.653 us; speedup vs baseline: 2.6568x; 1.7562x over previous
//
#include <hip/hip_runtime.h>
#include <stdint.h>

#define N_NODES_C 262144
#define N_EDGES_C 2097152
#define NB_C      8192      // graphs
#define NEG_SLOPE_C 0.2f

typedef __attribute__((ext_vector_type(4))) float f32x4;
typedef __attribute__((ext_vector_type(8))) short short8;
typedef unsigned int u32;

static __device__ __forceinline__ unsigned short f2bf(float f) {
    unsigned int u = __builtin_bit_cast(unsigned int, f);
    unsigned int r = (u + 0x7FFFu + ((u >> 16) & 1u)) >> 16;
    return (unsigned short)r;
}
static __device__ __forceinline__ float bf2f(unsigned short u) {
    unsigned int x = ((unsigned int)u) << 16;
    return __builtin_bit_cast(float, x);
}

// ---------------- transpose + cast: out[c][r] = bf16(in[r][c]) ----------------
__global__ void transpose_cast(const float* __restrict__ in,
                               unsigned short* __restrict__ out, int R, int Cc) {
    int i = blockIdx.x * blockDim.x + threadIdx.x;
    if (i < R * Cc) {
        int r = i / Cc, c = i % Cc;
        out[(size_t)c * R + r] = f2bf(in[i]);
    }
}

// ---------------- CSR build ----------------
__global__ void zero_u32(u32* __restrict__ p, int n) {
    int i = blockIdx.x * blockDim.x + threadIdx.x;
    int stride = gridDim.x * blockDim.x;
    for (int k = i; k < n; k += stride) p[k] = 0u;
}

__global__ void hist_kernel(const int* __restrict__ dst, u32* __restrict__ counts) {
    int i = blockIdx.x * blockDim.x + threadIdx.x;
    int stride = gridDim.x * blockDim.x;
    for (int e = i; e < N_EDGES_C; e += stride)
        atomicAdd(&counts[dst[e]], 1u);
}

__global__ __launch_bounds__(256) void scan_a(const u32* __restrict__ counts,
                                              u32* __restrict__ row_start,
                                              u32* __restrict__ partials) {
    __shared__ u32 sd[256];
    const int t = threadIdx.x;
    const int base = blockIdx.x * 1024 + t * 4;
    uint4 c = *(const uint4*)(counts + base);
    u32 s = c.x + c.y + c.z + c.w;
    sd[t] = s;
    __syncthreads();
    for (int off = 1; off < 256; off <<= 1) {
        u32 v = (t >= off) ? sd[t - off] : 0u;
        __syncthreads();
        sd[t] += v;
        __syncthreads();
    }
    u32 excl = sd[t] - s;
    row_start[base + 0] = excl;
    row_start[base + 1] = excl + c.x;
    row_start[base + 2] = excl + c.x + c.y;
    row_start[base + 3] = excl + c.x + c.y + c.z;
    if (t == 255) partials[blockIdx.x] = sd[255];
}

__global__ __launch_bounds__(256) void scan_b(u32* __restrict__ partials) {
    __shared__ u32 sd[256];
    const int t = threadIdx.x;
    u32 s = partials[t];
    sd[t] = s;
    __syncthreads();
    for (int off = 1; off < 256; off <<= 1) {
        u32 v = (t >= off) ? sd[t - off] : 0u;
        __syncthreads();
        sd[t] += v;
        __syncthreads();
    }
    partials[t] = sd[t] - s;   // exclusive block offsets
}

__global__ __launch_bounds__(256) void scan_c(u32* __restrict__ row_start,
                                              u32* __restrict__ cursor,
                                              const u32* __restrict__ partials) {
    int i = blockIdx.x * 256 + threadIdx.x;  // 1024 blocks
    u32 v = row_start[i] + partials[i >> 10];
    row_start[i] = v;
    cursor[i] = v;
    if (i == 0) row_start[N_NODES_C] = N_EDGES_C;
}

__global__ void scatter_kernel(const int* __restrict__ src, const int* __restrict__ dst,
                               u32* __restrict__ cursor, int* __restrict__ sorted_src) {
    int i = blockIdx.x * blockDim.x + threadIdx.x;
    int stride = gridDim.x * blockDim.x;
    for (int e = i; e < N_EDGES_C; e += stride) {
        u32 pos = atomicAdd(&cursor[dst[e]], 1u);
        sorted_src[pos] = src[e];
    }
}

// ---------------- node transform via MFMA: h = X @ W, a_s, a_d ----------------
// Wave handles 16 node-rows. B-frags (W^T) register-resident.
template <int LAYER>
__global__ __launch_bounds__(256) void transform_mfma(
    const float* __restrict__ xin,
    const unsigned short* __restrict__ Wt,   // bf16 [64][64]: Wt[o][k]
    const float* __restrict__ att_s, const float* __restrict__ att_d,
    const float* __restrict__ bias_in,       // layer2 only: b1
    unsigned short* __restrict__ h_bf,
    float* __restrict__ a_s, float* __restrict__ a_d)
{
    const int lane = threadIdx.x & 63;
    const int wid  = threadIdx.x >> 6;
    const int col  = lane & 15;
    const int kl   = lane >> 4;   // 0..3

    short8 bfr[4][2];
    #pragma unroll
    for (int t = 0; t < 4; ++t)
        #pragma unroll
        for (int kh = 0; kh < 2; ++kh)
            bfr[t][kh] = *(const short8*)(Wt + (t * 16 + col) * 64 + kh * 32 + kl * 8);

    float attS[4], attD[4];
    #pragma unroll
    for (int t = 0; t < 4; ++t) {
        attS[t] = att_s[t * 16 + col];
        attD[t] = att_d[t * 16 + col];
    }
    float bofs[2][8];
    if constexpr (LAYER == 2) {
        #pragma unroll
        for (int kh = 0; kh < 2; ++kh)
            #pragma unroll
            for (int j = 0; j < 8; ++j) bofs[kh][j] = bias_in[kh * 32 + kl * 8 + j];
    }

    const int g = blockIdx.x * 4 + wid;   // 4096 blocks -> 16384 groups exactly
    const int arow = g * 16 + col;
    const float* xp = xin + (size_t)arow * 64;
    short8 af[2];
    #pragma unroll
    for (int kh = 0; kh < 2; ++kh) {
        f32x4 v0 = *(const f32x4*)(xp + kh * 32 + kl * 8);
        f32x4 v1 = *(const f32x4*)(xp + kh * 32 + kl * 8 + 4);
        short8 a;
        #pragma unroll
        for (int j = 0; j < 4; ++j) {
            float f0 = v0[j], f1 = v1[j];
            if constexpr (LAYER == 2) { f0 += bofs[kh][j]; f1 += bofs[kh][4 + j]; }
            a[j] = (short)f2bf(f0);
            a[4 + j] = (short)f2bf(f1);
        }
        af[kh] = a;
    }

    f32x4 acc[4];
    #pragma unroll
    for (int t = 0; t < 4; ++t) {
        f32x4 d = {0.f, 0.f, 0.f, 0.f};
        d = __builtin_amdgcn_mfma_f32_16x16x32_bf16(af[0], bfr[t][0], d, 0, 0, 0);
        d = __builtin_amdgcn_mfma_f32_16x16x32_bf16(af[1], bfr[t][1], d, 0, 0, 0);
        acc[t] = d;
    }

    float ps[4] = {0.f, 0.f, 0.f, 0.f}, pd[4] = {0.f, 0.f, 0.f, 0.f};
    #pragma unroll
    for (int t = 0; t < 4; ++t) {
        #pragma unroll
        for (int j = 0; j < 4; ++j) {
            int node = g * 16 + kl * 4 + j;
            h_bf[(size_t)node * 64 + t * 16 + col] = f2bf(acc[t][j]);
            ps[j] += acc[t][j] * attS[t];
            pd[j] += acc[t][j] * attD[t];
        }
    }
    #pragma unroll
    for (int m = 1; m < 16; m <<= 1) {
        #pragma unroll
        for (int j = 0; j < 4; ++j) {
            ps[j] += __shfl_xor(ps[j], m, 64);
            pd[j] += __shfl_xor(pd[j], m, 64);
        }
    }
    if (col == 0) {
        #pragma unroll
        for (int j = 0; j < 4; ++j) {
            int node = g * 16 + kl * 4 + j;
            a_s[node] = ps[j];
            a_d[node] = pd[j];
        }
    }
}

// ---------------- fused GAT aggregate (per dst node, no atomics) ----------------
__global__ __launch_bounds__(256) void gat_aggregate(
    const u32* __restrict__ row_start, const int* __restrict__ sorted_src,
    const float* __restrict__ a_s, const float* __restrict__ a_d,
    const unsigned short* __restrict__ h_bf, float* __restrict__ agg)
{
    const int lane = threadIdx.x & 63;
    const int wid = (blockIdx.x * blockDim.x + threadIdx.x) >> 6;
    const int nw  = (gridDim.x * blockDim.x) >> 6;
    for (int node = wid; node < N_NODES_C; node += nw) {
        const u32 beg = row_start[node], end = row_start[node + 1];
        float acc = 0.f;
        if (beg < end) {
            const float ad = a_d[node];
            float m = -3.0e38f, l = 0.f;
            for (u32 base = beg; base < end; base += 64) {
                u32 i = base + lane;
                bool valid = i < end;
                int s = valid ? sorted_src[i] : 0;
                float e = valid ? a_s[s] + ad : -3.0e38f;
                e = e > 0.f ? e : NEG_SLOPE_C * e;
                float cm = e;
                #pragma unroll
                for (int off = 32; off; off >>= 1) cm = fmaxf(cm, __shfl_xor(cm, off, 64));
                float mn = fmaxf(m, cm);
                float p = valid ? __expf(e - mn) : 0.f;
                #pragma unroll
                for (int off = 32; off; off >>= 1) p += __shfl_xor(p, off, 64);
                l = l * __expf(m - mn) + p;
                m = mn;
            }
            const float inv = 1.f / l;
            for (u32 base = beg; base < end; base += 64) {
                u32 i = base + lane;
                bool valid = i < end;
                int s = valid ? sorted_src[i] : 0;
                float e = valid ? a_s[s] + ad : 0.f;
                e = e > 0.f ? e : NEG_SLOPE_C * e;
                float alpha = valid ? __expf(e - m) * inv : 0.f;
                int cnt = (int)min(64u, end - base);
                for (int j = 0; j < cnt; ++j) {
                    float al = __shfl(alpha, j, 64);
                    int sj = __shfl(s, j, 64);
                    acc += al * bf2f(h_bf[(size_t)sj * 64 + lane]);
                }
            }
        }
        agg[(size_t)node * 64 + lane] = acc;
    }
}

// ---------------- FC head ----------------
// g[r][k] = agg[r*2048+k] + b2[k&63]; fbuf = relu(g @ Wf1 + bf1) via MFMA
__global__ __launch_bounds__(256) void fc1_mfma(
    const float* __restrict__ agg, const float* __restrict__ b2,
    const unsigned short* __restrict__ Wf1t,  // bf16 [256][2048]
    const float* __restrict__ bf1, float* __restrict__ fbuf)
{
    const int lane = threadIdx.x & 63;
    const int w    = threadIdx.x >> 6;   // col block: cols w*64 .. w*64+63
    const int col  = lane & 15;
    const int kl   = lane >> 4;
    const int rbase = blockIdx.x * 32;   // 256 blocks

    float bo[2][8];
    #pragma unroll
    for (int p = 0; p < 2; ++p)
        #pragma unroll
        for (int j = 0; j < 8; ++j) bo[p][j] = b2[p * 32 + kl * 8 + j];

    f32x4 acc[2][4];
    #pragma unroll
    for (int rt = 0; rt < 2; ++rt)
        #pragma unroll
        for (int ct = 0; ct < 4; ++ct) acc[rt][ct] = (f32x4){0.f, 0.f, 0.f, 0.f};

    for (int ks = 0; ks < 64; ++ks) {
        const int k0 = ks * 32 + kl * 8;
        const int p = ks & 1;
        short8 af[2];
        #pragma unroll
        for (int rt = 0; rt < 2; ++rt) {
            const float* ap = agg + (size_t)(rbase + rt * 16 + col) * 2048 + k0;
            f32x4 v0 = *(const f32x4*)ap;
            f32x4 v1 = *(const f32x4*)(ap + 4);
            short8 a;
            #pragma unroll
            for (int j = 0; j < 4; ++j) {
                a[j]     = (short)f2bf(v0[j] + bo[p][j]);
                a[4 + j] = (short)f2bf(v1[j] + bo[p][4 + j]);
            }
            af[rt] = a;
        }
        #pragma unroll
        for (int ct = 0; ct < 4; ++ct) {
            short8 b = *(const short8*)(Wf1t + (size_t)(w * 64 + ct * 16 + col) * 2048 + k0);
            #pragma unroll
            for (int rt = 0; rt < 2; ++rt)
                acc[rt][ct] = __builtin_amdgcn_mfma_f32_16x16x32_bf16(af[rt], b, acc[rt][ct], 0, 0, 0);
        }
    }
    #pragma unroll
    for (int rt = 0; rt < 2; ++rt) {
        #pragma unroll
        for (int ct = 0; ct < 4; ++ct) {
            const int ocol = w * 64 + ct * 16 + col;
            const float bias = bf1[ocol];
            #pragma unroll
            for (int j = 0; j < 4; ++j) {
                int row = rbase + rt * 16 + kl * 4 + j;
                float v = acc[rt][ct][j] + bias;
                fbuf[(size_t)row * 256 + ocol] = v > 0.f ? v : 0.f;
            }
        }
    }
}

__global__ __launch_bounds__(256) void fc2_f32(
    const float* __restrict__ fbuf, const float* __restrict__ Wf2, // [256][32]
    const float* __restrict__ bf2v, float* __restrict__ out)
{
    __shared__ float w[256 * 32];
    for (int i = threadIdx.x; i < 256 * 32; i += 256) w[i] = Wf2[i];
    __syncthreads();
    int tid = blockIdx.x * 256 + threadIdx.x;
    int b = tid >> 5, o = tid & 31;
    float acc = bf2v[o];
    const float* fp = fbuf + (size_t)b * 256;
    for (int j = 0; j < 256; j += 4) {
        f32x4 f4 = *(const f32x4*)(fp + j);
        acc += f4[0] * w[(j + 0) * 32 + o];
        acc += f4[1] * w[(j + 1) * 32 + o];
        acc += f4[2] * w[(j + 2) * 32 + o];
        acc += f4[3] * w[(j + 3) * 32 + o];
    }
    out[(size_t)b * 32 + o] = acc;
}

// ---------------- launch ----------------
extern "C" void kernel_launch(void* const* d_in, const int* in_sizes, int n_in,
                              void* d_out, int out_size, void* d_ws, size_t ws_size,
                              hipStream_t stream)
{
    const float* x    = (const float*)d_in[0];
    const int*   ei   = (const int*)d_in[1];
    const float* W1   = (const float*)d_in[2];
    const float* as1  = (const float*)d_in[3];
    const float* ad1  = (const float*)d_in[4];
    const float* b1   = (const float*)d_in[5];
    const float* W2   = (const float*)d_in[6];
    const float* as2  = (const float*)d_in[7];
    const float* ad2  = (const float*)d_in[8];
    const float* b2   = (const float*)d_in[9];
    const float* Wf1  = (const float*)d_in[10];
    const float* bf1  = (const float*)d_in[11];
    const float* Wf2  = (const float*)d_in[12];
    const float* bf2v = (const float*)d_in[13];

    const int* src = ei;
    const int* dst = ei + N_EDGES_C;

    char* ws = (char*)d_ws;
    unsigned short* h_bf = (unsigned short*)ws; ws += (size_t)N_NODES_C * 64 * 2;
    float* agg          = (float*)ws;          ws += (size_t)N_NODES_C * 64 * 4;
    float* a_s          = (float*)ws;          ws += (size_t)N_NODES_C * 4;
    float* a_d          = (float*)ws;          ws += (size_t)N_NODES_C * 4;
    u32* counts         = (u32*)ws;            ws += (size_t)N_NODES_C * 4;
    u32* row_start      = (u32*)ws;            ws += (size_t)(N_NODES_C + 4) * 4;
    u32* cursor         = (u32*)ws;            ws += (size_t)N_NODES_C * 4;
    int* sorted_src     = (int*)ws;            ws += (size_t)N_EDGES_C * 4;
    u32* partials       = (u32*)ws;            ws += 256 * 4;
    float* fbuf         = (float*)ws;          ws += (size_t)NB_C * 256 * 4;
    unsigned short* Wt1 = (unsigned short*)ws; ws += 64 * 64 * 2;
    unsigned short* Wt2 = (unsigned short*)ws; ws += 64 * 64 * 2;
    unsigned short* Wf1t = (unsigned short*)ws; ws += (size_t)256 * 2048 * 2;

    // ---- weight transposes (bf16) ----
    transpose_cast<<<16, 256, 0, stream>>>(W1, Wt1, 64, 64);
    transpose_cast<<<16, 256, 0, stream>>>(W2, Wt2, 64, 64);
    transpose_cast<<<2048, 256, 0, stream>>>(Wf1, Wf1t, 2048, 256);

    // ---- CSR build (edge_index only; shared by both layers) ----
    zero_u32<<<256, 256, 0, stream>>>(counts, N_NODES_C);
    hist_kernel<<<2048, 256, 0, stream>>>(dst, counts);
    scan_a<<<256, 256, 0, stream>>>(counts, row_start, partials);
    scan_b<<<1, 256, 0, stream>>>(partials);
    scan_c<<<1024, 256, 0, stream>>>(row_start, cursor, partials);
    scatter_kernel<<<2048, 256, 0, stream>>>(src, dst, cursor, sorted_src);

    // ---- layer 1 ----
    transform_mfma<1><<<4096, 256, 0, stream>>>(x, Wt1, as1, ad1, nullptr, h_bf, a_s, a_d);
    gat_aggregate<<<16384, 256, 0, stream>>>(row_start, sorted_src, a_s, a_d, h_bf, agg);

    // ---- layer 2 ----
    transform_mfma<2><<<4096, 256, 0, stream>>>(agg, Wt2, as2, ad2, b1, h_bf, a_s, a_d);
    gat_aggregate<<<16384, 256, 0, stream>>>(row_start, sorted_src, a_s, a_d, h_bf, agg);

    // ---- FC head ----
    fc1_mfma<<<256, 256, 0, stream>>>(agg, b2, Wf1t, bf1, fbuf);
    fc2_f32<<<1024, 256, 0, stream>>>(fbuf, Wf2, bf2v, (float*)d_out);
}